// Round 6
// baseline (125.850 us; speedup 1.0000x reference)
//
#include <hip/hip_runtime.h>
#include <stdint.h>
#include <math.h>

#define NROWS 8192
#define DDIM  256
#define BM    64
#define BN    128
#define GJ    8                         // column groups (grid.y)
#define COLS_PER_GROUP (NROWS / GJ)     // 1024

constexpr float INV_T  = 1.0f / 0.07f;  // fixed LSE max M0 = 1/T (|logit| <= 1/T)
constexpr float LOG2E  = 1.44269504f;
constexpr float K1     = INV_T * LOG2E; // exp2 arg: fma(acc, K1, -K1)

typedef __bf16 bf16x8 __attribute__((ext_vector_type(8)));
typedef float  f32x4  __attribute__((ext_vector_type(4)));

__device__ __forceinline__ void async_copy16(const uint16_t* g, uint16_t* l) {
    __builtin_amdgcn_global_load_lds(
        (const __attribute__((address_space(1))) uint32_t*)g,
        (__attribute__((address_space(3))) uint32_t*)l, 16, 0, 0);
}

__device__ inline uint16_t f2bf(float f) {
    uint32_t u = __float_as_uint(f);
    u += 0x7fffu + ((u >> 16) & 1u);    // RNE
    return (uint16_t)(u >> 16);
}

// Kernel 1: normalize rows to unit length (bf16 out). One wave per row.
// q-row waves ALSO compute l_pos = cos(q_i, k_i) in fp32 (reference is fp32;
// the old bf16-GEMM-derived l_pos was strictly less accurate). This lets the
// main kernel drop the diagonal special-case entirely: LSE over
// [l_pos, row-with-diag-masked(-10)] == log(full unmasked row sum) because the
// first column equals the diagonal and exp(-10/T) ~ e^-143 is negligible.
__global__ __launch_bounds__(256) void norm_convert_kernel(
    const float* __restrict__ fq, const float* __restrict__ fk,
    uint16_t* __restrict__ qb, uint16_t* __restrict__ kb,
    float* __restrict__ lpT)
{
    const int wave = threadIdx.x >> 6;
    const int lane = threadIdx.x & 63;
    const int row  = blockIdx.x * 4 + wave;

    if (row < NROWS) {
        // q-row: normalize q, and fold in the paired k-row for l_pos.
        const float* qsrc = fq + (size_t)row * DDIM;
        const float* ksrc = fk + (size_t)row * DDIM;
        float4 vq = ((const float4*)qsrc)[lane];
        float4 vk = ((const float4*)ksrc)[lane];
        float ssq = vq.x*vq.x + vq.y*vq.y + vq.z*vq.z + vq.w*vq.w;
        float ssk = vk.x*vk.x + vk.y*vk.y + vk.z*vk.z + vk.w*vk.w;
        float dqk = vq.x*vk.x + vq.y*vk.y + vq.z*vk.z + vq.w*vk.w;
        #pragma unroll
        for (int m = 1; m < 64; m <<= 1) {
            ssq += __shfl_xor(ssq, m, 64);
            ssk += __shfl_xor(ssk, m, 64);
            dqk += __shfl_xor(dqk, m, 64);
        }
        float r = rsqrtf(ssq);
        ushort4 o;
        o.x = f2bf(vq.x * r); o.y = f2bf(vq.y * r); o.z = f2bf(vq.z * r); o.w = f2bf(vq.w * r);
        ((ushort4*)(qb + (size_t)row * DDIM))[lane] = o;
        if (lane == 0) {
            float denom = fmaxf(sqrtf(ssq) * sqrtf(ssk), 1e-8f);
            lpT[row] = (dqk / denom) * INV_T;
        }
    } else {
        const int r_ = row - NROWS;
        const float* src = fk + (size_t)r_ * DDIM;
        float4 v = ((const float4*)src)[lane];
        float ss = v.x*v.x + v.y*v.y + v.z*v.z + v.w*v.w;
        #pragma unroll
        for (int m = 1; m < 64; m <<= 1) ss += __shfl_xor(ss, m, 64);
        float r = rsqrtf(ss);
        ushort4 o;
        o.x = f2bf(v.x * r); o.y = f2bf(v.y * r); o.z = f2bf(v.z * r); o.w = f2bf(v.w * r);
        ((ushort4*)(kb + (size_t)r_ * DDIM))[lane] = o;
    }
}

// Kernel 2: round-0 structure (proven) at BM=64 for 3 blocks/CU occupancy
// (48 KiB LDS/block; was 80 KiB -> 2 blocks/CU). The kernel is latency/sync-
// bound (64 drain-barriers, no pipe >40%), so the third co-resident block
// overlaps one block's barrier drain with another's compute (m114 mechanism).
// Swizzles proven conflict-free in rounds 4/5 (SQ_LDS_BANK_CONFLICT = 0).
// Epilogue: plain exp-accumulate of the FULL row (diag included; see kernel 1).
// 4 waves in 2x2, each 32x64 via 16x16x32 bf16 MFMA.
__global__ __launch_bounds__(256, 3) void nce_main_kernel(
    const uint16_t* __restrict__ qb, const uint16_t* __restrict__ kb,
    float* __restrict__ gpl)
{
    __shared__ __align__(16) uint16_t lds_q[BM * DDIM];     // 32768 B, swizzled
    __shared__ __align__(16) uint16_t lds_k[2 * BN * 32];   // 16384 B, 2 bufs, swizzled

    const int tid    = threadIdx.x;
    const int wave   = tid >> 6;
    const int lane   = tid & 63;
    const int quad   = lane >> 4;
    const int lanelo = lane & 15;
    const int wr     = wave >> 1;
    const int wc     = wave & 1;
    const int rowBase      = blockIdx.x * BM;
    const int colGroupBase = blockIdx.y * COLS_PER_GROUP;

    // ---- Stage Q tile once: 2048 chunks of 16B, 8 instrs/wave, source-swizzled.
    #pragma unroll
    for (int i = 0; i < 8; ++i) {
        int S   = (wave * 8 + i) * 64 + lane;           // lds chunk id
        int row = S >> 5;
        int ch  = (S & 31) ^ (row & 31);                // swizzle: source chunk
        async_copy16(qb + (size_t)(rowBase + row) * DDIM + ch * 8,
                     lds_q + (size_t)(wave * 8 + i) * 512);
    }

    // ---- K staging lane constants (chunk = 16B; 4 chunks per 32-col row).
    int kS0   = wave * 128 + lane;                      // i=0 chunk id in 512-chunk buffer
    int krow0 = kS0 >> 2;
    int kch0  = (lane & 3) ^ ((krow0 >> 1) & 3);        // proven source swizzle
    int krow1 = (kS0 + 64) >> 2;
    int kch1  = (lane & 3) ^ ((krow1 >> 1) & 3);
    const uint16_t* kbase0 = kb + (size_t)(colGroupBase + krow0) * DDIM + kch0 * 8;
    const uint16_t* kbase1 = kb + (size_t)(colGroupBase + krow1) * DDIM + kch1 * 8;
    uint16_t* kl0 = lds_k + wave * 1024;                // wave-uniform dest (i=0)

    // phase 0 (jt=0, kk=0) into buf 0
    async_copy16(kbase0, kl0);
    async_copy16(kbase1, kl0 + 512);
    __syncthreads();    // Q + first K chunk visible

    // ---- Fragment address constants.
    int rq[2], rq31[2];
    #pragma unroll
    for (int mt = 0; mt < 2; ++mt) {
        rq[mt]   = wr * 32 + mt * 16 + lanelo;
        rq31[mt] = rq[mt] & 31;
    }
    int bvoff[4];
    #pragma unroll
    for (int nt = 0; nt < 4; ++nt) {
        int rk = wc * 64 + nt * 16 + lanelo;
        bvoff[nt] = rk * 32 + (quad ^ ((lanelo >> 1) & 3)) * 8;  // proven read swizzle
    }

    float l_run[8];
    #pragma unroll
    for (int i = 0; i < 8; ++i) l_run[i] = 0.f;

    for (int jt = 0; jt < 8; ++jt) {
        f32x4 acc[2][4];
        #pragma unroll
        for (int mt = 0; mt < 2; ++mt)
            #pragma unroll
            for (int nt = 0; nt < 4; ++nt)
                acc[mt][nt] = (f32x4){0.f, 0.f, 0.f, 0.f};

        #pragma unroll
        for (int kk = 0; kk < 8; ++kk) {
            const int p    = (jt << 3) + kk;
            const int buf  = p & 1;
            const int nbuf = buf ^ 1;

            // Issue next chunk's loads (drained only at the NEXT barrier).
            if (p < 63) {
                int np  = p + 1;
                int off = ((np >> 3) << 15) + ((np & 7) << 5);  // njt*128*256 + nkk*32
                uint16_t* ld = lds_k + nbuf * 4096 + wave * 1024;
                async_copy16(kbase0 + off, ld);
                async_copy16(kbase1 + off, ld + 512);
            }

            // Compute on buf.
            bf16x8 av[2], bv[4];
            #pragma unroll
            for (int mt = 0; mt < 2; ++mt) {
                int chp = ((kk << 2) + quad) ^ rq31[mt];
                av[mt] = *(const bf16x8*)&lds_q[rq[mt] * 256 + chp * 8];
            }
            #pragma unroll
            for (int nt = 0; nt < 4; ++nt)
                bv[nt] = *(const bf16x8*)&lds_k[buf * 4096 + bvoff[nt]];
            #pragma unroll
            for (int mt = 0; mt < 2; ++mt)
                #pragma unroll
                for (int nt = 0; nt < 4; ++nt)
                    acc[mt][nt] = __builtin_amdgcn_mfma_f32_16x16x32_bf16(av[mt], bv[nt], acc[mt][nt], 0, 0, 0);

            __syncthreads();    // publish chunk p+1's writes / guard buf reuse
        }

        // Epilogue: fixed-max exp accumulate, full row, no diag special-case.
        #pragma unroll
        for (int mt = 0; mt < 2; ++mt) {
            #pragma unroll
            for (int rg = 0; rg < 4; ++rg) {
                float s = 0.f;
                #pragma unroll
                for (int nt = 0; nt < 4; ++nt)
                    s += exp2f(fmaf(acc[mt][nt][rg], K1, -K1));
                l_run[mt * 4 + rg] += s;
            }
        }
    }

    // Cross-lane reduce over the 16 lanelo lanes (same row, different cols).
    #pragma unroll
    for (int i = 0; i < 8; ++i) {
        float v = l_run[i];
        v += __shfl_xor(v, 1, 64);
        v += __shfl_xor(v, 2, 64);
        v += __shfl_xor(v, 4, 64);
        v += __shfl_xor(v, 8, 64);
        l_run[i] = v;
    }
    // All LDS reads/writes done (last barrier passed; no loads in flight).
    float* pl = (float*)lds_k;      // 128 floats scratch
    if (lanelo == 0) {
        #pragma unroll
        for (int mt = 0; mt < 2; ++mt)
            #pragma unroll
            for (int rg = 0; rg < 4; ++rg) {
                int lr = wr * 32 + mt * 16 + quad * 4 + rg;
                pl[wc * 64 + lr] = l_run[mt * 4 + rg];
            }
    }
    __syncthreads();
    if (tid < 64) {
        float L = pl[tid] + pl[64 + tid];
        gpl[(size_t)blockIdx.y * NROWS + rowBase + tid] = L;
    }
}

// Kernel 3: merge GJ partial sums; loss = M0 + log(L) - l_pos/T.
// (L already contains the diagonal = positive term; see kernel 1 comment.)
__global__ __launch_bounds__(256) void finalize_kernel(
    const float* __restrict__ gpl, const float* __restrict__ lpT,
    float* __restrict__ out)
{
    int t = blockIdx.x * 256 + threadIdx.x;
    if (t >= NROWS) return;
    float L = 0.f;
    #pragma unroll
    for (int g = 0; g < GJ; ++g) L += gpl[g * NROWS + t];
    out[t] = INV_T + __logf(L) - lpT[t];
}

extern "C" void kernel_launch(void* const* d_in, const int* in_sizes, int n_in,
                              void* d_out, int out_size, void* d_ws, size_t ws_size,
                              hipStream_t stream) {
    const float* fq = (const float*)d_in[0];
    const float* fk = (const float*)d_in[1];
    char* ws = (char*)d_ws;
    // layout: qb 4MB | kb 4MB | lpT 32KB | gpl 256KB
    uint16_t* qb  = (uint16_t*)(ws);
    uint16_t* kb  = (uint16_t*)(ws + 4194304);
    float*    lpT = (float*)(ws + 8388608);
    float*    gpl = (float*)(ws + 8421376);

    norm_convert_kernel<<<(2 * NROWS) / 4, 256, 0, stream>>>(fq, fk, qb, kb, lpT);
    dim3 grid(NROWS / BM, GJ);
    nce_main_kernel<<<grid, 256, 0, stream>>>(qb, kb, gpl);
    finalize_kernel<<<NROWS / 256, 256, 0, stream>>>(gpl, lpT, (float*)d_out);
}

// Round 7
// 125.528 us; speedup vs baseline: 1.0026x; 1.0026x over previous
//
#include <hip/hip_runtime.h>
#include <stdint.h>
#include <math.h>

#define NROWS 8192
#define DDIM  256
#define BM    128
#define BN    128
#define GJ    8                         // column groups (grid.y)
#define COLS_PER_GROUP (NROWS / GJ)     // 1024

constexpr float INV_T  = 1.0f / 0.07f;  // fixed LSE max M0 = 1/T (|logit| <= 1/T)
constexpr float LOG2E  = 1.44269504f;
constexpr float K1     = INV_T * LOG2E; // exp2 arg: fma(acc, K1, -K1)

typedef __bf16 bf16x8 __attribute__((ext_vector_type(8)));
typedef float  f32x4  __attribute__((ext_vector_type(4)));

__device__ __forceinline__ void async_copy16(const uint16_t* g, uint16_t* l) {
    __builtin_amdgcn_global_load_lds(
        (const __attribute__((address_space(1))) uint32_t*)g,
        (__attribute__((address_space(3))) uint32_t*)l, 16, 0, 0);
}

__device__ inline uint16_t f2bf(float f) {
    uint32_t u = __float_as_uint(f);
    u += 0x7fffu + ((u >> 16) & 1u);    // RNE
    return (uint16_t)(u >> 16);
}

// Kernel 1: normalize rows to unit length (bf16 out). One wave per row.
// q-row waves ALSO compute l_pos = cos(q_i,k_i) in fp32 (validated round 6):
// LSE over [l_pos, row-with-diag-masked(-10)] == log(full unmasked row sum),
// so the main kernel needs no diagonal special-case.
__global__ __launch_bounds__(256) void norm_convert_kernel(
    const float* __restrict__ fq, const float* __restrict__ fk,
    uint16_t* __restrict__ qb, uint16_t* __restrict__ kb,
    float* __restrict__ lpT)
{
    const int wave = threadIdx.x >> 6;
    const int lane = threadIdx.x & 63;
    const int row  = blockIdx.x * 4 + wave;

    if (row < NROWS) {
        const float* qsrc = fq + (size_t)row * DDIM;
        const float* ksrc = fk + (size_t)row * DDIM;
        float4 vq = ((const float4*)qsrc)[lane];
        float4 vk = ((const float4*)ksrc)[lane];
        float ssq = vq.x*vq.x + vq.y*vq.y + vq.z*vq.z + vq.w*vq.w;
        float ssk = vk.x*vk.x + vk.y*vk.y + vk.z*vk.z + vk.w*vk.w;
        float dqk = vq.x*vk.x + vq.y*vk.y + vq.z*vk.z + vq.w*vk.w;
        #pragma unroll
        for (int m = 1; m < 64; m <<= 1) {
            ssq += __shfl_xor(ssq, m, 64);
            ssk += __shfl_xor(ssk, m, 64);
            dqk += __shfl_xor(dqk, m, 64);
        }
        float r = rsqrtf(ssq);
        ushort4 o;
        o.x = f2bf(vq.x * r); o.y = f2bf(vq.y * r); o.z = f2bf(vq.z * r); o.w = f2bf(vq.w * r);
        ((ushort4*)(qb + (size_t)row * DDIM))[lane] = o;
        if (lane == 0) {
            float denom = fmaxf(sqrtf(ssq) * sqrtf(ssk), 1e-8f);
            lpT[row] = (dqk / denom) * INV_T;
        }
    } else {
        const int r_ = row - NROWS;
        const float* src = fk + (size_t)r_ * DDIM;
        float4 v = ((const float4*)src)[lane];
        float ss = v.x*v.x + v.y*v.y + v.z*v.z + v.w*v.w;
        #pragma unroll
        for (int m = 1; m < 64; m <<= 1) ss += __shfl_xor(ss, m, 64);
        float r = rsqrtf(ss);
        ushort4 o;
        o.x = f2bf(v.x * r); o.y = f2bf(v.y * r); o.z = f2bf(v.z * r); o.w = f2bf(v.w * r);
        ((ushort4*)(kb + (size_t)r_ * DDIM))[lane] = o;
    }
}

// Kernel 2: round-5 proven structure (BM=128, 4 waves 2x2, 16 MFMA/chunk,
// double-buffered BK=32, conflict-free swizzles) with ONE structural change:
// K staging via REGISTER pipeline depth 4 instead of global_load_lds.
// Why: the DMA was issued and vmcnt(0)-drained within the same ~950-cyc chunk,
// pinning every chunk at HBM latency (~900 cyc). Reg-staging gives each load
// 4 chunk-periods of slack; the compiler emits COUNTED vmcnt before each
// ds_write (register dep), and the barrier drains only local ds ops.
// gset indexed by (kk+1)&3 with kk fully unrolled -> compile-time (rule #20).
__global__ __launch_bounds__(256, 2) void nce_main_kernel(
    const uint16_t* __restrict__ qb, const uint16_t* __restrict__ kb,
    float* __restrict__ gpl)
{
    __shared__ __align__(16) uint16_t lds_q[BM * DDIM];     // 65536 B, swizzled
    __shared__ __align__(16) uint16_t lds_k[2 * BN * 32];   // 16384 B, 2 bufs, swizzled

    const int tid    = threadIdx.x;
    const int wave   = tid >> 6;
    const int lane   = tid & 63;
    const int quad   = lane >> 4;
    const int lanelo = lane & 15;
    const int wr     = wave >> 1;
    const int wc     = wave & 1;
    const int rowBase      = blockIdx.x * BM;
    const int colGroupBase = blockIdx.y * COLS_PER_GROUP;

    // ---- Stage Q tile once via DMA: 4096 chunks of 16B, source-swizzled.
    #pragma unroll
    for (int i = 0; i < 16; ++i) {
        int S   = (wave * 16 + i) * 64 + lane;          // lds chunk id
        int row = S >> 5;
        int ch  = (S & 31) ^ (row & 31);                // swizzle: source chunk
        async_copy16(qb + (size_t)(rowBase + row) * DDIM + ch * 8,
                     lds_q + (size_t)(wave * 16 + i) * 512);
    }

    // ---- K staging lane constants (chunk = 16B; 4 chunks per 32-col row).
    int kS0   = wave * 128 + lane;                      // i=0 chunk id in 512-chunk buffer
    int krow0 = kS0 >> 2;
    int kch0  = (lane & 3) ^ ((krow0 >> 1) & 3);        // proven source swizzle
    int krow1 = (kS0 + 64) >> 2;
    int kch1  = (lane & 3) ^ ((krow1 >> 1) & 3);
    const uint16_t* kbase0 = kb + (size_t)(colGroupBase + krow0) * DDIM + kch0 * 8;
    const uint16_t* kbase1 = kb + (size_t)(colGroupBase + krow1) * DDIM + kch1 * 8;
    uint16_t* kl0 = lds_k + wave * 1024;                // wave-uniform dest (i=0)

    // chunk 0 via DMA into buf 0 (drained by the prologue __syncthreads).
    async_copy16(kbase0, kl0);
    async_copy16(kbase1, kl0 + 512);

    // ---- Register FIFO prologue: chunks 1..4 into sets 1,2,3,0.
    uint4 gset[4][2];
    #pragma unroll
    for (int n = 1; n <= 4; ++n) {
        const int off = (n & 7) << 5;                   // n<8: off = n*32
        gset[n & 3][0] = *(const uint4*)(kbase0 + off);
        gset[n & 3][1] = *(const uint4*)(kbase1 + off);
    }

    __syncthreads();    // Q + chunk-0 DMA complete (full drain; FIFO clean after)

    // ---- Fragment address constants.
    int rq[4], rq31[4];
    #pragma unroll
    for (int mt = 0; mt < 4; ++mt) {
        rq[mt]   = wr * 64 + mt * 16 + lanelo;
        rq31[mt] = rq[mt] & 31;
    }
    int bvoff[4];
    #pragma unroll
    for (int nt = 0; nt < 4; ++nt) {
        int rk = wc * 64 + nt * 16 + lanelo;
        bvoff[nt] = rk * 32 + (quad ^ ((lanelo >> 1) & 3)) * 8;  // proven read swizzle
    }
    // Reg-staged ds_write dest: mirrors the DMA layout (base + lane*16B).
    const int wbase = wave * 1024 + lane * 8;           // uint16 units

    float l_run[16];
    #pragma unroll
    for (int i = 0; i < 16; ++i) l_run[i] = 0.f;

    for (int jt = 0; jt < 8; ++jt) {
        f32x4 acc[4][4];
        #pragma unroll
        for (int mt = 0; mt < 4; ++mt)
            #pragma unroll
            for (int nt = 0; nt < 4; ++nt)
                acc[mt][nt] = (f32x4){0.f, 0.f, 0.f, 0.f};

        #pragma unroll
        for (int kk = 0; kk < 8; ++kk) {
            const int p    = (jt << 3) + kk;
            const int buf  = p & 1;
            const int nbuf = buf ^ 1;
            const int s    = (kk + 1) & 3;              // compile-time FIFO slot

            // ds_read current chunk's fragments from buf.
            bf16x8 av[4], bv[4];
            #pragma unroll
            for (int mt = 0; mt < 4; ++mt) {
                int chp = ((kk << 2) + quad) ^ rq31[mt];
                av[mt] = *(const bf16x8*)&lds_q[rq[mt] * 256 + chp * 8];
            }
            #pragma unroll
            for (int nt = 0; nt < 4; ++nt)
                bv[nt] = *(const bf16x8*)&lds_k[buf * 4096 + bvoff[nt]];

            // ds_write chunk p+1 from gset[s] into nbuf (compiler emits a
            // counted vmcnt for the register dep -- no vmcnt(0) in the loop).
            {
                uint16_t* wp = lds_k + nbuf * 4096 + wbase;
                *(uint4*)wp         = gset[s][0];
                *(uint4*)(wp + 512) = gset[s][1];
            }
            // Refill slot s with chunk p+5 (4 periods of latency slack).
            {
                const int np  = (p + 5) & 63;           // tail wraps: loaded, never read
                const int off = ((np >> 3) << 15) + ((np & 7) << 5);
                gset[s][0] = *(const uint4*)(kbase0 + off);
                gset[s][1] = *(const uint4*)(kbase1 + off);
            }

            #pragma unroll
            for (int mt = 0; mt < 4; ++mt)
                #pragma unroll
                for (int nt = 0; nt < 4; ++nt)
                    acc[mt][nt] = __builtin_amdgcn_mfma_f32_16x16x32_bf16(av[mt], bv[nt], acc[mt][nt], 0, 0, 0);

            // Publish this chunk's ds_writes + retire reads (WAR), then sync.
            asm volatile("s_waitcnt lgkmcnt(0)" ::: "memory");
            asm volatile("s_barrier" ::: "memory");
        }

        // Epilogue: fixed-max exp accumulate, full row, no diag special-case.
        #pragma unroll
        for (int mt = 0; mt < 4; ++mt) {
            #pragma unroll
            for (int rg = 0; rg < 4; ++rg) {
                float s = 0.f;
                #pragma unroll
                for (int nt = 0; nt < 4; ++nt)
                    s += exp2f(fmaf(acc[mt][nt][rg], K1, -K1));
                l_run[mt * 4 + rg] += s;
            }
        }
    }

    // Cross-lane reduce over the 16 lanelo lanes (same row, different cols).
    #pragma unroll
    for (int i = 0; i < 16; ++i) {
        float v = l_run[i];
        v += __shfl_xor(v, 1, 64);
        v += __shfl_xor(v, 2, 64);
        v += __shfl_xor(v, 4, 64);
        v += __shfl_xor(v, 8, 64);
        l_run[i] = v;
    }
    // Full drain (incl. wrap loads) + resync before reusing lds_k as scratch.
    __syncthreads();

    float* pl = (float*)lds_k;      // 256 floats scratch
    if (lanelo == 0) {
        #pragma unroll
        for (int mt = 0; mt < 4; ++mt)
            #pragma unroll
            for (int rg = 0; rg < 4; ++rg) {
                int lr = wr * 64 + mt * 16 + quad * 4 + rg;
                pl[wc * 128 + lr] = l_run[mt * 4 + rg];
            }
    }
    __syncthreads();
    if (tid < 128) {
        float L = pl[tid] + pl[128 + tid];
        gpl[(size_t)blockIdx.y * NROWS + rowBase + tid] = L;
    }
}

// Kernel 3: merge GJ partial sums; loss = M0 + log(L) - l_pos/T.
// (L already contains the diagonal = positive term; see kernel 1.)
__global__ __launch_bounds__(256) void finalize_kernel(
    const float* __restrict__ gpl, const float* __restrict__ lpT,
    float* __restrict__ out)
{
    int t = blockIdx.x * 256 + threadIdx.x;
    if (t >= NROWS) return;
    float L = 0.f;
    #pragma unroll
    for (int g = 0; g < GJ; ++g) L += gpl[g * NROWS + t];
    out[t] = INV_T + __logf(L) - lpT[t];
}

extern "C" void kernel_launch(void* const* d_in, const int* in_sizes, int n_in,
                              void* d_out, int out_size, void* d_ws, size_t ws_size,
                              hipStream_t stream) {
    const float* fq = (const float*)d_in[0];
    const float* fk = (const float*)d_in[1];
    char* ws = (char*)d_ws;
    // layout: qb 4MB | kb 4MB | lpT 32KB | gpl 256KB
    uint16_t* qb  = (uint16_t*)(ws);
    uint16_t* kb  = (uint16_t*)(ws + 4194304);
    float*    lpT = (float*)(ws + 8388608);
    float*    gpl = (float*)(ws + 8421376);

    norm_convert_kernel<<<(2 * NROWS) / 4, 256, 0, stream>>>(fq, fk, qb, kb, lpT);
    dim3 grid(NROWS / BM, GJ);
    nce_main_kernel<<<grid, 256, 0, stream>>>(qb, kb, gpl);
    finalize_kernel<<<NROWS / 256, 256, 0, stream>>>(gpl, lpT, (float*)d_out);
}

// Round 8
// 105.640 us; speedup vs baseline: 1.1913x; 1.1883x over previous
//
#include <hip/hip_runtime.h>
#include <stdint.h>
#include <math.h>

#define NROWS 8192
#define DDIM  256
#define BM    128
#define BN    128
#define GJ    8                         // column groups (grid.y)
#define COLS_PER_GROUP (NROWS / GJ)     // 1024

constexpr float INV_T  = 1.0f / 0.07f;  // fixed LSE max M0 = 1/T (|logit| <= 1/T)
constexpr float LOG2E  = 1.44269504f;
constexpr float K1     = INV_T * LOG2E; // exp2 arg: fma(acc, K1, -K1)

typedef __bf16 bf16x8 __attribute__((ext_vector_type(8)));
typedef float  f32x4  __attribute__((ext_vector_type(4)));

__device__ __forceinline__ void async_copy16(const uint16_t* g, uint16_t* l) {
    __builtin_amdgcn_global_load_lds(
        (const __attribute__((address_space(1))) uint32_t*)g,
        (__attribute__((address_space(3))) uint32_t*)l, 16, 0, 0);
}

__device__ inline uint16_t f2bf(float f) {
    uint32_t u = __float_as_uint(f);
    u += 0x7fffu + ((u >> 16) & 1u);    // RNE
    return (uint16_t)(u >> 16);
}

// Kernel 1: normalize rows to unit length (bf16 out). One wave per row.
// q-row waves ALSO compute l_pos = cos(q_i,k_i) in fp32 (validated rounds 6/7):
// LSE over [l_pos, row-with-diag-masked(-10)] == log(full unmasked row sum),
// so the main kernel needs no diagonal special-case.
__global__ __launch_bounds__(256) void norm_convert_kernel(
    const float* __restrict__ fq, const float* __restrict__ fk,
    uint16_t* __restrict__ qb, uint16_t* __restrict__ kb,
    float* __restrict__ lpT)
{
    const int wave = threadIdx.x >> 6;
    const int lane = threadIdx.x & 63;
    const int row  = blockIdx.x * 4 + wave;

    if (row < NROWS) {
        const float* qsrc = fq + (size_t)row * DDIM;
        const float* ksrc = fk + (size_t)row * DDIM;
        float4 vq = ((const float4*)qsrc)[lane];
        float4 vk = ((const float4*)ksrc)[lane];
        float ssq = vq.x*vq.x + vq.y*vq.y + vq.z*vq.z + vq.w*vq.w;
        float ssk = vk.x*vk.x + vk.y*vk.y + vk.z*vk.z + vk.w*vk.w;
        float dqk = vq.x*vk.x + vq.y*vk.y + vq.z*vk.z + vq.w*vk.w;
        #pragma unroll
        for (int m = 1; m < 64; m <<= 1) {
            ssq += __shfl_xor(ssq, m, 64);
            ssk += __shfl_xor(ssk, m, 64);
            dqk += __shfl_xor(dqk, m, 64);
        }
        float r = rsqrtf(ssq);
        ushort4 o;
        o.x = f2bf(vq.x * r); o.y = f2bf(vq.y * r); o.z = f2bf(vq.z * r); o.w = f2bf(vq.w * r);
        ((ushort4*)(qb + (size_t)row * DDIM))[lane] = o;
        if (lane == 0) {
            float denom = fmaxf(sqrtf(ssq) * sqrtf(ssk), 1e-8f);
            lpT[row] = (dqk / denom) * INV_T;
        }
    } else {
        const int r_ = row - NROWS;
        const float* src = fk + (size_t)r_ * DDIM;
        float4 v = ((const float4*)src)[lane];
        float ss = v.x*v.x + v.y*v.y + v.z*v.z + v.w*v.w;
        #pragma unroll
        for (int m = 1; m < 64; m <<= 1) ss += __shfl_xor(ss, m, 64);
        float r = rsqrtf(ss);
        ushort4 o;
        o.x = f2bf(v.x * r); o.y = f2bf(v.y * r); o.z = f2bf(v.z * r); o.w = f2bf(v.w * r);
        ((ushort4*)(kb + (size_t)r_ * DDIM))[lane] = o;
    }
}

// Kernel 2: BARRIER-FREE K streaming. Each of 4 waves owns 128 rows x 32 cols
// of the 128x128 tile and stages its OWN 32-col K slice into a wave-private
// 2 x 2KB LDS double buffer via global_load_lds. Visibility of a wave's own
// DMA needs only its own vmcnt (per-wave counter) -> the K loop has ZERO
// __syncthreads. Unsynchronized waves slip in phase and hide each other's
// DMA latency on the CU (m114 overlap) -- the thing the lockstep barrier
// train (rounds 0-7) structurally prevented. No register K buffers -> no
// spill surface (rounds 1/7 regression). 16 MFMA per wave-chunk (proven
// thickness); all swizzles are the measured-conflict-free ones.
// WAR: DMA for chunk p+2 overwrites buf p&1; issued only after an explicit
// lgkmcnt(0) retires chunk p's ds_reads (sched_barrier pins MFMAs below).
__global__ __launch_bounds__(256, 2) void nce_main_kernel(
    const uint16_t* __restrict__ qb, const uint16_t* __restrict__ kb,
    float* __restrict__ gpl)
{
    __shared__ __align__(16) uint16_t lds_q[BM * DDIM];   // 65536 B, swizzled
    __shared__ __align__(16) uint16_t lds_k[8192];        // 4 waves x 2 bufs x 2KB = 16KB

    const int tid    = threadIdx.x;
    const int wave   = tid >> 6;
    const int lane   = tid & 63;
    const int quad   = lane >> 4;
    const int lanelo = lane & 15;
    const int rowBase      = blockIdx.x * BM;
    const int colGroupBase = blockIdx.y * COLS_PER_GROUP;

    // ---- Stage Q tile once: 4096 chunks of 16B, source-swizzled (proven).
    #pragma unroll
    for (int i = 0; i < 16; ++i) {
        int S   = (wave * 16 + i) * 64 + lane;          // lds chunk id
        int row = S >> 5;
        int ch  = (S & 31) ^ (row & 31);                // swizzle: source chunk
        async_copy16(qb + (size_t)(rowBase + row) * DDIM + ch * 8,
                     lds_q + (size_t)(wave * 16 + i) * 512);
    }

    // ---- Wave-private K staging constants. Slice buffer = [32 rows][32 k]
    // bf16 = 2KB = 128 chunks of 16B; 2 DMA instr per chunk per wave.
    // Chunk id S = i*64+lane -> row r = i*16+(lane>>2), pos = lane&3; source
    // chunk = pos ^ ((r>>1)&3) = (lane&3)^((lane>>3)&3) for both i (proven
    // conflict-free scheme from rounds 4-7).
    const int c0 = (lane & 3) ^ ((lane >> 3) & 3);
    const uint16_t* kpb0 = kb + (size_t)(colGroupBase + wave * 32 +      (lane >> 2)) * DDIM + c0 * 8;
    const uint16_t* kpb1 = kb + (size_t)(colGroupBase + wave * 32 + 16 + (lane >> 2)) * DDIM + c0 * 8;
    uint16_t* kw = lds_k + wave * 2048;                 // uint16 units; 2 bufs x 1024

    // chunks 0 (buf0) and 1 (buf1)
    async_copy16(kpb0,      kw);
    async_copy16(kpb1,      kw + 512);
    async_copy16(kpb0 + 32, kw + 1024);
    async_copy16(kpb1 + 32, kw + 1536);

    __syncthreads();    // Q visible to all waves; all prologue DMAs drained.

    // ---- Fragment address constants.
    // B read: slice row rs = nt*16+lanelo, k-chunk quad stored at
    // quad ^ ((rs>>1)&3) = quad ^ ((lanelo>>1)&3).
    int bvoff[2];
    #pragma unroll
    for (int nt = 0; nt < 2; ++nt)
        bvoff[nt] = (nt * 16 + lanelo) * 32 + (quad ^ ((lanelo >> 1) & 3)) * 8;

    float l_run[32];
    #pragma unroll
    for (int i = 0; i < 32; ++i) l_run[i] = 0.f;

    for (int jt = 0; jt < 8; ++jt) {
        f32x4 acc[8][2];
        #pragma unroll
        for (int mt = 0; mt < 8; ++mt)
            #pragma unroll
            for (int nt = 0; nt < 2; ++nt)
                acc[mt][nt] = (f32x4){0.f, 0.f, 0.f, 0.f};

        #pragma unroll
        for (int kk = 0; kk < 8; ++kk) {
            const int p = (jt << 3) + kk;

            // Wait own chunk p (leaves p+1's 2 loads in flight). Per-wave
            // counter -- no cross-wave coupling.
            asm volatile("s_waitcnt vmcnt(2)" ::: "memory");

            // ds_read fragments: 8 A (whole 128-row Q column-of-K) + 2 B.
            bf16x8 av[8], bv[2];
            #pragma unroll
            for (int mt = 0; mt < 8; ++mt) {
                int rq  = mt * 16 + lanelo;
                int chp = ((kk << 2) + quad) ^ (lanelo + ((mt & 1) << 4));
                av[mt] = *(const bf16x8*)&lds_q[rq * 256 + chp * 8];
            }
            const int bufo = (p & 1) << 10;
            bv[0] = *(const bf16x8*)&lds_k[wave * 2048 + bufo + bvoff[0]];
            bv[1] = *(const bf16x8*)&lds_k[wave * 2048 + bufo + bvoff[1]];

            // Retire reads, then overwrite buf p&1 with chunk p+2
            // (~1.7 chunk-periods of latency slack before its vmcnt wait).
            asm volatile("s_waitcnt lgkmcnt(0)" ::: "memory");
            {
                const int np  = (p + 2) & 63;           // tail wraps: never read
                const int off = ((np >> 3) << 15) + ((np & 7) << 5);
                async_copy16(kpb0 + off, kw + bufo);
                async_copy16(kpb1 + off, kw + bufo + 512);
            }
            __builtin_amdgcn_sched_barrier(0);          // pin MFMAs below the wait+DMA

            #pragma unroll
            for (int mt = 0; mt < 8; ++mt)
                #pragma unroll
                for (int nt = 0; nt < 2; ++nt)
                    acc[mt][nt] = __builtin_amdgcn_mfma_f32_16x16x32_bf16(
                        av[mt], bv[nt], acc[mt][nt], 0, 0, 0);
        }

        // Epilogue: fixed-max exp accumulate, full row, no diag special-case.
        #pragma unroll
        for (int mt = 0; mt < 8; ++mt) {
            #pragma unroll
            for (int rg = 0; rg < 4; ++rg) {
                float s = exp2f(fmaf(acc[mt][0][rg], K1, -K1))
                        + exp2f(fmaf(acc[mt][1][rg], K1, -K1));
                l_run[mt * 4 + rg] += s;
            }
        }
    }

    // Cross-lane reduce over the 16 lanelo lanes (same row, different cols).
    #pragma unroll
    for (int i = 0; i < 32; ++i) {
        float v = l_run[i];
        v += __shfl_xor(v, 1, 64);
        v += __shfl_xor(v, 2, 64);
        v += __shfl_xor(v, 4, 64);
        v += __shfl_xor(v, 8, 64);
        l_run[i] = v;
    }

    // Drain wrap DMAs (vmcnt(0) implicit in __syncthreads) + resync all waves
    // before reusing lds_k as cross-wave scratch.
    __syncthreads();

    float* pl = (float*)lds_k;      // 4 waves x 128 rows = 512 floats (2KB)
    if (lanelo == 0) {
        #pragma unroll
        for (int mt = 0; mt < 8; ++mt)
            #pragma unroll
            for (int rg = 0; rg < 4; ++rg)
                pl[wave * 128 + mt * 16 + quad * 4 + rg] = l_run[mt * 4 + rg];
    }
    __syncthreads();
    if (tid < 128) {
        float L = pl[tid] + pl[128 + tid] + pl[256 + tid] + pl[384 + tid];
        gpl[(size_t)blockIdx.y * NROWS + rowBase + tid] = L;
    }
}

// Kernel 3: merge GJ partial sums; loss = M0 + log(L) - l_pos/T.
// (L already contains the diagonal = positive term; see kernel 1.)
__global__ __launch_bounds__(256) void finalize_kernel(
    const float* __restrict__ gpl, const float* __restrict__ lpT,
    float* __restrict__ out)
{
    int t = blockIdx.x * 256 + threadIdx.x;
    if (t >= NROWS) return;
    float L = 0.f;
    #pragma unroll
    for (int g = 0; g < GJ; ++g) L += gpl[g * NROWS + t];
    out[t] = INV_T + __logf(L) - lpT[t];
}

extern "C" void kernel_launch(void* const* d_in, const int* in_sizes, int n_in,
                              void* d_out, int out_size, void* d_ws, size_t ws_size,
                              hipStream_t stream) {
    const float* fq = (const float*)d_in[0];
    const float* fk = (const float*)d_in[1];
    char* ws = (char*)d_ws;
    // layout: qb 4MB | kb 4MB | lpT 32KB | gpl 256KB
    uint16_t* qb  = (uint16_t*)(ws);
    uint16_t* kb  = (uint16_t*)(ws + 4194304);
    float*    lpT = (float*)(ws + 8388608);
    float*    gpl = (float*)(ws + 8421376);

    norm_convert_kernel<<<(2 * NROWS) / 4, 256, 0, stream>>>(fq, fk, qb, kb, lpT);
    dim3 grid(NROWS / BM, GJ);
    nce_main_kernel<<<grid, 256, 0, stream>>>(qb, kb, gpl);
    finalize_kernel<<<NROWS / 256, 256, 0, stream>>>(gpl, lpT, (float*)d_out);
}